// Round 17
// baseline (219.231 us; speedup 1.0000x reference)
//
#include <hip/hip_runtime.h>
#include <hip/hip_fp16.h>

#define N_NODES  100000
#define N_EDGES  1200000
#define N_GRAPHS 1024
#define F        64
#define BN_EPS   1e-5f
#define NBUCK    ((N_NODES + 255) / 256)       // 391 buckets of 256 node IDs
#define NBLK     512                            // chunks (one per hist block)
#define CHUNK    ((N_EDGES + NBLK - 1) / NBLK)  // 2344 edges per chunk
#define MT       128                            // GEMM nodes per block
#define GEMM_BLOCKS ((N_NODES + MT - 1) / MT)   // 782
#define CE       3584                           // per-bucket edge capacity

// ---------------------------------------------------------------------------
// prep: fused [gemm_uz | chunk counting-sort]. GEMM blocks: Uh=feats@Wself,
// Zh=feats@Wneigh (fp16). Sort blocks: counting-sort own chunk's edges by
// bucket into pairs[c*CHUNK ...] (packed local_dst<<24|src) + write per-chunk
// bucket offsets Ct[c][0..NBUCK]. Replaces chist+cscan+bscan+cscat.
// ---------------------------------------------------------------------------
__global__ __launch_bounds__(256) void prep(
    const float* __restrict__ feats, const float* __restrict__ Wself,
    const float* __restrict__ Wneigh, __half* __restrict__ Uh,
    __half* __restrict__ Zh, const int* __restrict__ src,
    const int* __restrict__ dst, int* __restrict__ pairs,
    int* __restrict__ Ct, int* __restrict__ hgbits) {
  __shared__ __align__(16) char smraw[MT * 65 * 4 + 64 * 128 * 4];
  int t = threadIdx.x;

  if (blockIdx.x >= GEMM_BLOCKS) {
    // ---- chunk counting-sort ----
    int* loff = (int*)smraw;             // NBUCK+1
    int* lcur = loff + (NBUCK + 1);      // NBUCK
    int* ssc  = lcur + NBUCK;            // 256
    int c = blockIdx.x - GEMM_BLOCKS;
    int zidx = c * 256 + t;
    if (zidx < N_GRAPHS * F) hgbits[zidx] = 0;
    for (int i = t; i < NBUCK; i += 256) lcur[i] = 0;
    __syncthreads();
    int e0 = c * CHUNK, e1 = e0 + CHUNK;
    if (e1 > N_EDGES) e1 = N_EDGES;
    for (int e = e0 + t; e < e1; e += 256) atomicAdd(&lcur[dst[e] >> 8], 1);
    __syncthreads();
    // exclusive scan of NBUCK counts (2/thread)
    int c0 = 2 * t, c1 = 2 * t + 1;
    int x0 = (c0 < NBUCK) ? lcur[c0] : 0;
    int x1 = (c1 < NBUCK) ? lcur[c1] : 0;
    int ps = x0 + x1;
    ssc[t] = ps;
    __syncthreads();
    for (int off = 1; off < 256; off <<= 1) {
      int u = (t >= off) ? ssc[t - off] : 0;
      __syncthreads();
      ssc[t] += u;
      __syncthreads();
    }
    int excl = ssc[t] - ps;
    if (c0 < NBUCK) loff[c0] = excl;
    if (c1 < NBUCK) loff[c1] = excl + x0;
    if (t == 255) loff[NBUCK] = ssc[255];
    __syncthreads();
    for (int i = t; i < NBUCK; i += 256) lcur[i] = loff[i];
    __syncthreads();
    for (int e = e0 + t; e < e1; e += 256) {
      int d = dst[e];
      int pos = atomicAdd(&lcur[d >> 8], 1);
      pairs[(size_t)c * CHUNK + pos] =
          (int)((((unsigned)d & 255u) << 24) | (unsigned)src[e]);
    }
    for (int i = t; i < NBUCK + 1; i += 256)
      Ct[(size_t)c * (NBUCK + 1) + i] = loff[i];
    return;
  }

  // ---- GEMM part (R13 proven) ----
  float* As = (float*)smraw;                   // MT x 65
  float* Ws = (float*)(smraw + MT * 65 * 4);   // 64 x 128
  int mbase = blockIdx.x * MT;

  for (int i = t; i < 64 * 128; i += 256) {
    int k = i >> 7, j = i & 127;
    Ws[i] = (j < 64) ? Wself[k * 64 + j] : Wneigh[k * 64 + (j - 64)];
  }
#pragma unroll
  for (int s = 0; s < 8; s++) {
    int idx = (s * 256 + t) * 4;
    int m = idx >> 6, k = idx & 63;
    int gm = mbase + m;
    float4 v = (gm < N_NODES) ? *(const float4*)(feats + (size_t)gm * F + k)
                              : make_float4(0.f, 0.f, 0.f, 0.f);
    float* d = As + m * 65 + k;
    d[0] = v.x; d[1] = v.y; d[2] = v.z; d[3] = v.w;
  }
  __syncthreads();

  int wave = t >> 6, lane = t & 63;
  int jq = lane & 3, nq = lane >> 2;
  int half = wave & 1;
  int mb = (wave >> 1) * 64 + 4 * nq;
  int joff = half * 64 + jq * 16;

  float acc[4][16];
#pragma unroll
  for (int i = 0; i < 4; i++)
#pragma unroll
    for (int c = 0; c < 16; c++) acc[i][c] = 0.f;

#pragma unroll 4
  for (int k = 0; k < 64; k++) {
    float a0 = As[(mb + 0) * 65 + k];
    float a1 = As[(mb + 1) * 65 + k];
    float a2 = As[(mb + 2) * 65 + k];
    float a3 = As[(mb + 3) * 65 + k];
    const float4* wr = (const float4*)(Ws + k * 128 + joff);
    float4 w4[4];
    w4[0] = wr[0]; w4[1] = wr[1]; w4[2] = wr[2]; w4[3] = wr[3];
    const float* w = (const float*)w4;
#pragma unroll
    for (int c = 0; c < 16; c++) {
      float wv = w[c];
      acc[0][c] += a0 * wv;
      acc[1][c] += a1 * wv;
      acc[2][c] += a2 * wv;
      acc[3][c] += a3 * wv;
    }
  }

  __half* outp = half ? Zh : Uh;
  int jbase = jq * 16;
#pragma unroll
  for (int i = 0; i < 4; i++) {
    int gm = mbase + mb + i;
    if (gm < N_NODES) {
#pragma unroll
      for (int c4 = 0; c4 < 4; c4++) {
        union { __half h[4]; uint2 u; } pk;
        pk.h[0] = __float2half_rn(acc[i][c4 * 4 + 0]);
        pk.h[1] = __float2half_rn(acc[i][c4 * 4 + 1]);
        pk.h[2] = __float2half_rn(acc[i][c4 * 4 + 2]);
        pk.h[3] = __float2half_rn(acc[i][c4 * 4 + 3]);
        *(uint2*)(outp + (size_t)gm * F + jbase + c4 * 4) = pk.u;
      }
    }
  }
}

// ---------------------------------------------------------------------------
// gather_place v2: one 1024-thread block per bucket.
// Phase 1: threads 0..511 each own a chunk; read the bucket's segment bounds
// from Ct (L2-hot), histogram local_dst (LDS int atomics), then scatter the
// segment into eidx_l via LDS cursors. Phase 2: gather + SAGE + ReLU +
// per-graph max (R16 proven, LDS-broadcast neighbor ids).
// ---------------------------------------------------------------------------
__global__ __launch_bounds__(1024) void gather_place(
    const __half* __restrict__ Uh, const __half* __restrict__ Zh,
    const int* __restrict__ pairs, const int* __restrict__ Ct,
    const float* __restrict__ bneigh, const int* __restrict__ gids,
    int* __restrict__ hgbits) {
  __shared__ int eidx_l[CE];     // 14.3 KB
  __shared__ int rsl[256];
  __shared__ int lh[256];
  __shared__ int cur[256];
  int b = blockIdx.x, t = threadIdx.x;
  int nb0 = b << 8;

  if (t < 256) lh[t] = 0;
  __syncthreads();

  // segment bounds for my chunk
  int segs = 0, sege = 0;
  if (t < NBLK) {
    size_t base = (size_t)t * (NBUCK + 1);
    int o0 = Ct[base + b];
    int o1 = Ct[base + b + 1];
    segs = t * CHUNK + o0;
    sege = t * CHUNK + o1;
    for (int e = segs; e < sege; e++)
      atomicAdd(&lh[((unsigned)pairs[e]) >> 24], 1);
  }
  __syncthreads();

  if (t < 256) cur[t] = lh[t];
  __syncthreads();
  for (int off = 1; off < 256; off <<= 1) {
    int u = (t < 256 && t >= off) ? cur[t - off] : 0;
    __syncthreads();
    if (t < 256) cur[t] += u;
    __syncthreads();
  }
  if (t < 256) { int ex = cur[t] - lh[t]; rsl[t] = ex; cur[t] = ex; }
  __syncthreads();

  if (t < NBLK) {
    for (int e = segs; e < sege; e++) {
      unsigned p = (unsigned)pairs[e];
      int pos = atomicAdd(&cur[p >> 24], 1);
      if (pos < CE) eidx_l[pos] = (int)(p & 0xFFFFFFu);
    }
  }
  __syncthreads();

  // --- phase 2: gather + SAGE update + ReLU + per-graph max ---
  int wave = t >> 6, lane = t & 63;
  int fl = lane & 15, sub = lane >> 4;
  float4 b4 = *(const float4*)(bneigh + 4 * fl);
  int nl = wave * 16;
  int nend = nl + 16;
  if (nb0 + nl >= N_NODES) return;
  if (nb0 + nend > N_NODES) nend = N_NODES - nb0;

  int curg = gids[nb0 + nl];
  float4 gmax = {0.f, 0.f, 0.f, 0.f};

  for (; nl < nend; nl++) {
    int node = nb0 + nl;
    int rr  = rsl[nl];
    int deg = lh[nl];
    uint2 ur = *(const uint2*)(Uh + (size_t)node * F + 4 * fl);
    float sx = 0.f, sy = 0.f, sz = 0.f, sw = 0.f;
    for (int jj = 0; jj < deg; jj += 16) {
      int j0 = jj + sub;
      int s0 = (j0      < deg) ? eidx_l[rr + j0]      : 0;  // LDS broadcast
      int s1 = (j0 + 4  < deg) ? eidx_l[rr + j0 + 4]  : 0;
      int s2 = (j0 + 8  < deg) ? eidx_l[rr + j0 + 8]  : 0;
      int s3 = (j0 + 12 < deg) ? eidx_l[rr + j0 + 12] : 0;
      uint2 z0 = *(const uint2*)(Zh + (size_t)s0 * F + 4 * fl);
      uint2 z1 = *(const uint2*)(Zh + (size_t)s1 * F + 4 * fl);
      uint2 z2 = *(const uint2*)(Zh + (size_t)s2 * F + 4 * fl);
      uint2 z3 = *(const uint2*)(Zh + (size_t)s3 * F + 4 * fl);
      if (j0 < deg) {
        float2 f0 = __half22float2(*(__half2*)&z0.x);
        float2 f1 = __half22float2(*(__half2*)&z0.y);
        sx += f0.x; sy += f0.y; sz += f1.x; sw += f1.y;
      }
      if (j0 + 4 < deg) {
        float2 f0 = __half22float2(*(__half2*)&z1.x);
        float2 f1 = __half22float2(*(__half2*)&z1.y);
        sx += f0.x; sy += f0.y; sz += f1.x; sw += f1.y;
      }
      if (j0 + 8 < deg) {
        float2 f0 = __half22float2(*(__half2*)&z2.x);
        float2 f1 = __half22float2(*(__half2*)&z2.y);
        sx += f0.x; sy += f0.y; sz += f1.x; sw += f1.y;
      }
      if (j0 + 12 < deg) {
        float2 f0 = __half22float2(*(__half2*)&z3.x);
        float2 f1 = __half22float2(*(__half2*)&z3.y);
        sx += f0.x; sy += f0.y; sz += f1.x; sw += f1.y;
      }
    }
    sx += __shfl_xor(sx, 16); sy += __shfl_xor(sy, 16);
    sz += __shfl_xor(sz, 16); sw += __shfl_xor(sw, 16);
    sx += __shfl_xor(sx, 32); sy += __shfl_xor(sy, 32);
    sz += __shfl_xor(sz, 32); sw += __shfl_xor(sw, 32);
    float inv = 1.0f / fmaxf((float)deg, 1.0f);

    int g = gids[node];
    if (g != curg) {
      if (sub == 0) {
        int* hp = hgbits + (size_t)curg * F + 4 * fl;
        atomicMax(hp + 0, __float_as_int(gmax.x));
        atomicMax(hp + 1, __float_as_int(gmax.y));
        atomicMax(hp + 2, __float_as_int(gmax.z));
        atomicMax(hp + 3, __float_as_int(gmax.w));
      }
      curg = g; gmax = make_float4(0.f, 0.f, 0.f, 0.f);
    }

    float2 uf0 = __half22float2(*(__half2*)&ur.x);
    float2 uf1 = __half22float2(*(__half2*)&ur.y);
    gmax.x = fmaxf(gmax.x, fmaxf(uf0.x + sx * inv + b4.x, 0.f));
    gmax.y = fmaxf(gmax.y, fmaxf(uf0.y + sy * inv + b4.y, 0.f));
    gmax.z = fmaxf(gmax.z, fmaxf(uf1.x + sz * inv + b4.z, 0.f));
    gmax.w = fmaxf(gmax.w, fmaxf(uf1.y + sw * inv + b4.w, 0.f));
  }
  if (sub == 0) {
    int* hp = hgbits + (size_t)curg * F + 4 * fl;
    atomicMax(hp + 0, __float_as_int(gmax.x));
    atomicMax(hp + 1, __float_as_int(gmax.y));
    atomicMax(hp + 2, __float_as_int(gmax.z));
    atomicMax(hp + 3, __float_as_int(gmax.w));
  }
}

// ---------------------------------------------------------------------------
// MLP head: weights staged in LDS once, 8 graphs per block.
// ---------------------------------------------------------------------------
#define GPB 8
__global__ __launch_bounds__(128) void mlp(
    const float* __restrict__ hg,
    const float* __restrict__ W1, const float* __restrict__ b1,
    const float* __restrict__ g1, const float* __restrict__ be1,
    const float* __restrict__ rm1, const float* __restrict__ rv1,
    const float* __restrict__ W2, const float* __restrict__ b2,
    const float* __restrict__ g2, const float* __restrict__ be2,
    const float* __restrict__ rm2, const float* __restrict__ rv2,
    const float* __restrict__ W3, const float* __restrict__ b3,
    float* __restrict__ out) {
  __shared__ float W1s[64 * 128];
  __shared__ float W2s[128 * 64];
  __shared__ float W3s[64];
  __shared__ float sc1[128], sh1[128], b1s[128];
  __shared__ float sc2[64],  sh2[64],  b2s[64];
  __shared__ float s0[64], s1[128], s2[64];
  int t = threadIdx.x;

  for (int i = t; i < 64 * 128; i += 128) W1s[i] = W1[i];
  for (int i = t; i < 128 * 64; i += 128) W2s[i] = W2[i];
  if (t < 64) W3s[t] = W3[t];
  {
    float iv = rsqrtf(rv1[t] + BN_EPS);
    float sc = g1[t] * iv;
    sc1[t] = sc; sh1[t] = be1[t] - rm1[t] * sc; b1s[t] = b1[t];
  }
  if (t < 64) {
    float iv = rsqrtf(rv2[t] + BN_EPS);
    float sc = g2[t] * iv;
    sc2[t] = sc; sh2[t] = be2[t] - rm2[t] * sc; b2s[t] = b2[t];
  }
  __syncthreads();

  for (int gg = 0; gg < GPB; gg++) {
    int g = blockIdx.x * GPB + gg;
    if (t < 64) s0[t] = hg[(size_t)g * F + t];
    __syncthreads();
    {
      float acc = b1s[t];
      for (int i = 0; i < 64; i++) acc += s0[i] * W1s[i * 128 + t];
      acc = fmaxf(acc, 0.0f);
      s1[t] = acc * sc1[t] + sh1[t];
    }
    __syncthreads();
    if (t < 64) {
      float acc = b2s[t];
      for (int i = 0; i < 128; i++) acc += s1[i] * W2s[i * 64 + t];
      acc = fmaxf(acc, 0.0f);
      s2[t] = acc * sc2[t] + sh2[t];
    }
    __syncthreads();
    if (t < 64) {
      float p = s2[t] * W3s[t];
      for (int off = 32; off > 0; off >>= 1) p += __shfl_down(p, off);
      if (t == 0) out[g] = p + b3[0];
    }
    __syncthreads();
  }
}

// ---------------------------------------------------------------------------
extern "C" void kernel_launch(void* const* d_in, const int* in_sizes, int n_in,
                              void* d_out, int out_size, void* d_ws, size_t ws_size,
                              hipStream_t stream) {
  const float* feats  = (const float*)d_in[0];
  const int*   src    = (const int*)d_in[1];
  const int*   dst    = (const int*)d_in[2];
  const int*   gids   = (const int*)d_in[3];
  const float* Wself  = (const float*)d_in[4];
  const float* Wneigh = (const float*)d_in[5];
  const float* bneigh = (const float*)d_in[6];
  const float* W1  = (const float*)d_in[7];
  const float* b1  = (const float*)d_in[8];
  const float* g1  = (const float*)d_in[9];
  const float* be1 = (const float*)d_in[10];
  const float* rm1 = (const float*)d_in[11];
  const float* rv1 = (const float*)d_in[12];
  const float* W2  = (const float*)d_in[13];
  const float* b2  = (const float*)d_in[14];
  const float* g2  = (const float*)d_in[15];
  const float* be2 = (const float*)d_in[16];
  const float* rm2 = (const float*)d_in[17];
  const float* rv2 = (const float*)d_in[18];
  const float* W3  = (const float*)d_in[19];
  const float* b3  = (const float*)d_in[20];

  // ws layout: Uh | Zh | hgbits | Ct | pairs
  __half* Uh   = (__half*)d_ws;                      // N_NODES*64 halves
  __half* Zh   = Uh + (size_t)N_NODES * F;           // N_NODES*64 halves
  int* hgbits  = (int*)(Zh + (size_t)N_NODES * F);   // N_GRAPHS*F (zeroed in prep)
  int* Ct      = hgbits + (size_t)N_GRAPHS * F;      // NBLK*(NBUCK+1)
  int* pairs   = Ct + (size_t)NBLK * (NBUCK + 1);    // NBLK*CHUNK

  prep<<<GEMM_BLOCKS + NBLK, 256, 0, stream>>>(feats, Wself, Wneigh, Uh, Zh,
                                               src, dst, pairs, Ct, hgbits);
  gather_place<<<NBUCK, 1024, 0, stream>>>(Uh, Zh, pairs, Ct, bneigh,
                                           gids, hgbits);
  mlp<<<N_GRAPHS / GPB, 128, 0, stream>>>((const float*)hgbits,
                                          W1, b1, g1, be1, rm1, rv1,
                                          W2, b2, g2, be2, rm2, rv2, W3, b3,
                                          (float*)d_out);
}